// Round 8
// baseline (585.277 us; speedup 1.0000x reference)
//
#include <hip/hip_runtime.h>
#include <math.h>

#define KS 48
#define TLEN 512
#define BN 1024
#define START_S 46
#define STOP_S 47
#define NEGV -10000.0f
#define PF 8   // emission prefetch depth

typedef float v2f __attribute__((ext_vector_type(2)));

__device__ __forceinline__ float bcast_lane0(float v) {
    return __builtin_bit_cast(float, __builtin_amdgcn_readfirstlane(__builtin_bit_cast(int, v)));
}

// wave argmax, first-index tie-break (matches jnp.argmax; validated rounds 1-7)
__device__ __forceinline__ void wargmax(float& bv, int& bi) {
    #pragma unroll
    for (int off = 32; off; off >>= 1) {
        float ov = __shfl_xor(bv, off, 64);
        int   oi = __shfl_xor(bi, off, 64);
        if (ov > bv || (ov == bv && oi < bi)) { bv = ov; bi = oi; }
    }
}

// grid = 2048, 1-wave blocks (R2 concurrent structure — fusion falsified 2x).
// ROUND-15: R6 ground truth: vit scan 303us owns the wall; its excess over fwd
// (~450cy/step) tracks the in-scan argmax tree (~135 VALU/step), not memory
// (R1-R4 eliminated every memory mechanism). Synthesis of two proven pieces:
//   scan  = R0's max-only pk core (no index tree, ~60 inst/step), storing the
//           vit register itself (V_t rows, f32, fire-and-forget — R0-proven);
//   btrace= chunk-stage V rows into LDS (R2-proven movement), recompute
//           tag_{t-1} = wargmax_p(V_{t-1}[p] + T[tag,p])  — exactly the
//           reference's bp=argmax(scores,axis=1) with validated tie-break.
// In-scan tree work (512 steps) moves to the backtrace (511 wargmax, ~75us).
__global__ __launch_bounds__(64) void crf15(
    const float* __restrict__ feats,   // [B, T, K]
    const float* __restrict__ trans,   // [K, K]  trans[next, prev]
    const int*   __restrict__ tags,    // [B, T]
    float*       __restrict__ out,     // [B] nll | [B] path_score | [B*T] paths
    float*       __restrict__ vw_g)    // [B, T, K] post-emission rows V_t
{
    const int lane = threadIdx.x;
    const bool act = lane < KS;

    __shared__ float xbuf[64];                     // exchange (single buffer:
                                                   // in-order DS => no WAR hazard)
    __shared__ float trans_sh[KS * KS];            // masked trans (backtrace)
    __shared__ __align__(16) float Vchunk[32 * KS];// 6 KB V-row chunk
    __shared__ unsigned char path_sh[TLEN];

    if (blockIdx.x < BN) {
        // ================= FORWARD (verbatim, absmax 0.0 for 7 rounds) =========
        const int b = blockIdx.x;
        const float* fb = feats + (size_t)b * TLEN * KS;
        const int*   tb = tags + (size_t)b * TLEN;

        float Erow[KS];   // exp(masked trans[next=lane][p]); exp(-10000)==0
        {
            const float* tr = trans + (act ? lane : 0) * KS;
            #pragma unroll
            for (int p = 0; p < KS; ++p) {
                float tv = act ? tr[p] : NEGV;
                if (lane == START_S) tv = NEGV;
                if (p == STOP_S)     tv = NEGV;
                Erow[p] = __expf(tv);
            }
        }
        float tstart = act ? trans[lane * KS + START_S] : NEGV;
        if (lane == START_S) tstart = NEGV;

        float alpha = (act ? fb[lane] : -INFINITY) + tstart;   // t=0 peeled, exact

        auto fstep = [&](float emv) {
            float s  = bcast_lane0(alpha);       // lane-0 alpha finite: valid shift
            float ue = __expf(alpha - s);        // -inf lanes -> 0
            xbuf[lane] = ue;                     // same-wave in-order LDS: no barrier
            const float4* uu = (const float4*)xbuf;
            v2f acc0 = {0.f, 0.f}, acc1 = {0.f, 0.f};
            #pragma unroll
            for (int g = 0; g < KS / 4; ++g) {
                float4 u = uu[g];
                v2f ua = {u.x, u.y}, ub = {u.z, u.w};
                v2f ea = {Erow[4 * g + 0], Erow[4 * g + 1]};
                v2f eb = {Erow[4 * g + 2], Erow[4 * g + 3]};
                acc0 = __builtin_elementwise_fma(ua, ea, acc0);
                acc1 = __builtin_elementwise_fma(ub, eb, acc1);
            }
            alpha = emv + s + __logf((acc0.x + acc0.y) + (acc1.x + acc1.y));
        };

        float em[PF];
        #pragma unroll
        for (int j = 0; j < PF; ++j)
            em[j] = act ? fb[(1 + j) * KS + lane] : -INFINITY;
        for (int c = 0; c < 63; ++c) {
            const int t0 = 1 + c * PF;
            float em_n[PF];
            #pragma unroll
            for (int j = 0; j < PF; ++j) {
                int tf = t0 + PF + j;
                em_n[j] = (act && tf < TLEN) ? fb[tf * KS + lane] : -INFINITY;
            }
            #pragma unroll
            for (int j = 0; j < PF; ++j) fstep(em[j]);
            #pragma unroll
            for (int j = 0; j < PF; ++j) em[j] = em_n[j];
        }
        #pragma unroll
        for (int j = 0; j < 7; ++j) fstep(em[j]);

        float tstop = act ? trans[STOP_S * KS + lane] : NEGV;
        if (lane == STOP_S) tstop = NEGV;
        float z = alpha + tstop;
        float mz = z;
        #pragma unroll
        for (int off = 32; off; off >>= 1)
            mz = fmaxf(mz, __shfl_xor(mz, off, 64));
        float se = __expf(z - mz);
        #pragma unroll
        for (int off = 32; off; off >>= 1)
            se += __shfl_xor(se, off, 64);
        float logZ = mz + __logf(se);

        float g = 0.0f;
        for (int t = lane; t < TLEN; t += 64) {
            int tg = tb[t];
            int pg = (t == 0) ? START_S : tb[t - 1];
            g += fb[t * KS + tg] + trans[tg * KS + pg];
        }
        #pragma unroll
        for (int off = 32; off; off >>= 1)
            g += __shfl_xor(g, off, 64);
        g += trans[STOP_S * KS + tb[TLEN - 1]];

        if (lane == 0) out[b] = logZ - g;
    } else {
        // ========== VITERBI: max-only scan (V-row store) + wargmax backtrace ===
        const int b = blockIdx.x - BN;
        const float* fb = feats + (size_t)b * TLEN * KS;
        float* vw = vw_g + (size_t)b * TLEN * KS;

        float Trow[KS];   // masked trans[next=lane][p] — reference's exact add
        {
            const float* tr = trans + (act ? lane : 0) * KS;
            #pragma unroll
            for (int p = 0; p < KS; ++p) {
                float tv = act ? tr[p] : NEGV;
                if (lane == START_S) tv = NEGV;
                if (p == STOP_S)     tv = NEGV;
                Trow[p] = tv;
            }
        }

        float vit = (lane == START_S) ? 0.0f : NEGV;

        // R0's proven max-only core: fp max exact -> any tree order bit-exact.
        auto vstep = [&](float emv, int t) {
            xbuf[lane] = vit;                    // in-order LDS, no barrier
            const float4* ww = (const float4*)xbuf;
            v2f m0 = {-3.0e38f, -3.0e38f}, m1 = {-3.0e38f, -3.0e38f};
            #pragma unroll
            for (int g = 0; g < KS / 4; ++g) {
                float4 w = ww[g];
                v2f wa = {w.x, w.y}, wb = {w.z, w.w};
                v2f ta = {Trow[4 * g + 0], Trow[4 * g + 1]};
                v2f tc = {Trow[4 * g + 2], Trow[4 * g + 3]};
                m0 = __builtin_elementwise_max(m0, wa + ta);   // v_pk ops
                m1 = __builtin_elementwise_max(m1, wb + tc);
            }
            v2f mm = __builtin_elementwise_max(m0, m1);
            float B = fmaxf(mm.x, mm.y);         // pre-emission max row (exact)
            vit = B + emv;                       // reference's exact add
            if (act) vw[t * KS + lane] = vit;    // V_t row, fire-and-forget
        };

        float em[PF];
        #pragma unroll
        for (int j = 0; j < PF; ++j)
            em[j] = act ? fb[j * KS + lane] : 0.0f;
        for (int c = 0; c < 64; ++c) {           // 512 = 64*8 exactly
            const int t0 = c * PF;
            float em_n[PF];
            if (c < 63) {
                #pragma unroll
                for (int j = 0; j < PF; ++j)
                    em_n[j] = act ? fb[(t0 + PF + j) * KS + lane] : 0.0f;
            }
            #pragma unroll
            for (int j = 0; j < PF; ++j) vstep(em[j], t0 + j);
            if (c < 63) {
                #pragma unroll
                for (int j = 0; j < PF; ++j) em[j] = em_n[j];
            }
        }

        // drain V stores before re-reading them in the backtrace
        asm volatile("s_waitcnt vmcnt(0)" ::: "memory");

        // ---- stage masked trans for backtrace (row-major [next][prev]) ----
        for (int idx = lane; idx < KS * KS; idx += 64) {
            int n = idx / KS, p = idx - n * KS;
            float tv = trans[idx];
            if (n == START_S) tv = NEGV;
            if (p == STOP_S)  tv = NEGV;
            trans_sh[idx] = tv;
        }

        float tstop = act ? trans[STOP_S * KS + lane] : NEGV;
        if (lane == STOP_S) tstop = NEGV;
        float term = act ? (vit + tstop) : -3.0e38f;
        float bv = term;
        int   bidx = act ? lane : 9999;
        wargmax(bv, bidx);
        int tag = __builtin_amdgcn_readfirstlane(bidx);
        if (lane == 0) {
            out[BN + b] = bv;
            path_sh[TLEN - 1] = (unsigned char)tag;
        }

        // ---- chunked backtrace: stage 32 V-rows, recompute argmax per step ----
        // tag_{t-1} = argmax_p( V_{t-1}[p] + T[tag_t, p] )  == reference's bp.
        for (int c = 15; c >= 0; --c) {
            float4 tmp[6];
            const float4* src = (const float4*)(vw + (size_t)c * 32 * KS);
            #pragma unroll
            for (int i = 0; i < 6; ++i)
                tmp[i] = src[lane + 64 * i];
            // same-wave in-order DS: prior chunk's chase reads precede these
            float4* dst = (float4*)Vchunk;
            #pragma unroll
            for (int i = 0; i < 6; ++i)
                dst[lane + 64 * i] = tmp[i];
            int thi = c * 32 + 32; if (thi > TLEN - 1) thi = TLEN - 1;
            const int tlo = c * 32 + 1;
            for (int t = thi; t >= tlo; --t) {
                float v  = Vchunk[((t - 1) & 31) * KS + lane];  // V_{t-1}[lane]
                float tr = trans_sh[tag * KS + lane];           // T[tag, lane]
                float sc = act ? (v + tr) : -INFINITY;          // scan's exact add
                float bvv = sc;
                int   bii = act ? lane : 9999;
                wargmax(bvv, bii);                              // first-index ties
                tag = __builtin_amdgcn_readfirstlane(bii);
                if (lane == 0) path_sh[t - 1] = (unsigned char)tag;
            }
        }
        __syncthreads();   // single wave: drains LDS before the read-back
        float* pout = out + 2 * BN + (size_t)b * TLEN;
        for (int t = lane; t < TLEN; t += 64)
            pout[t] = (float)path_sh[t];
    }
}

extern "C" void kernel_launch(void* const* d_in, const int* in_sizes, int n_in,
                              void* d_out, int out_size, void* d_ws, size_t ws_size,
                              hipStream_t stream) {
    const float* feats = (const float*)d_in[0];
    const float* trans = (const float*)d_in[1];
    const int*   tags  = (const int*)d_in[2];
    float*       out   = (float*)d_out;
    (void)in_sizes; (void)n_in; (void)out_size; (void)ws_size;

    // workspace: [B, T, K] f32 V-rows = 100.7 MB (ws_size >= this, verified R0)
    crf15<<<dim3(2 * BN), dim3(64), 0, stream>>>(feats, trans, tags, out,
                                                 (float*)d_ws);
}

// Round 9
// 356.006 us; speedup vs baseline: 1.6440x; 1.6440x over previous
//
#include <hip/hip_runtime.h>
#include <math.h>

#define KS 48
#define TLEN 512
#define BN 1024
#define START_S 46
#define STOP_S 47
#define NEGV -10000.0f
#define PF 8   // emission prefetch depth

typedef float v2f __attribute__((ext_vector_type(2)));

__device__ __forceinline__ float bcast_lane0(float v) {
    return __builtin_bit_cast(float, __builtin_amdgcn_readfirstlane(__builtin_bit_cast(int, v)));
}
__device__ __forceinline__ float rlane(float v, int k) {
    return __builtin_bit_cast(float, __builtin_amdgcn_readlane(__builtin_bit_cast(int, v), k));
}

// wave argmax, first-index tie-break (terminal only; validated rounds 1-7)
__device__ __forceinline__ void wargmax(float& bv, int& bi) {
    #pragma unroll
    for (int off = 32; off; off >>= 1) {
        float ov = __shfl_xor(bv, off, 64);
        int   oi = __shfl_xor(bi, off, 64);
        if (ov > bv || (ov == bv && oi < bi)) { bv = ov; bi = oi; }
    }
}

// grid = 2048, 1-wave blocks (concurrent structure — in-wave fusion falsified 2x).
// ROUND-16: accounting finally closes. fwd=586cy/step (~= op-chain theory).
// vit-tree=1420cy/step: the excess is ~40 serial v_cmp->v_cndmask pairs all
// contending for the single VCC reg (~10cy each, unreorderable) — NOT memory
// (R1-R4). R8's wargmax backtrace was 6 ds_bpermute/step (~1600cy) — also a
// compare/cross-lane chain. So: keep the three proven-CHEAP pieces and drop
// the two proven-EXPENSIVE ones:
//   scan   = R0 max-only pk core (v_pk_add/v_pk_max, ZERO compares) storing
//            pre-emission B rows f32 (R0 semantics, fire-and-forget);
//   chase  = LDS-staged chunks (R8 movement: 16 B-rows + 16 e-rows) + R0's
//            ballot+ctz (compare writes an SGPR pair once, ctz is SALU;
//            chain = trans_sh read ~120 + ~40cy, no VCC ping-pong);
//   fwd    = verbatim (absmax 0.0 x8).
// LDS = 16KB phase-union pool -> 10 blocks/CU.
__global__ __launch_bounds__(64) void crf16(
    const float* __restrict__ feats,   // [B, T, K]
    const float* __restrict__ trans,   // [K, K]  trans[next, prev]
    const int*   __restrict__ tags,    // [B, T]
    float*       __restrict__ out,     // [B] nll | [B] path_score | [B*T] paths
    float*       __restrict__ vw_g)    // [B, T, K] pre-emission max rows B_t
{
    const int lane = threadIdx.x;
    const bool act = lane < KS;

    __shared__ __align__(16) unsigned char pool[16384];
    float* xbuf = (float*)pool;                    // scan phase: 256B exchange

    if (blockIdx.x < BN) {
        // ================= FORWARD (verbatim, absmax 0.0 for 8 rounds) =========
        const int b = blockIdx.x;
        const float* fb = feats + (size_t)b * TLEN * KS;
        const int*   tb = tags + (size_t)b * TLEN;

        float Erow[KS];   // exp(masked trans[next=lane][p]); exp(-10000)==0
        {
            const float* tr = trans + (act ? lane : 0) * KS;
            #pragma unroll
            for (int p = 0; p < KS; ++p) {
                float tv = act ? tr[p] : NEGV;
                if (lane == START_S) tv = NEGV;
                if (p == STOP_S)     tv = NEGV;
                Erow[p] = __expf(tv);
            }
        }
        float tstart = act ? trans[lane * KS + START_S] : NEGV;
        if (lane == START_S) tstart = NEGV;

        float alpha = (act ? fb[lane] : -INFINITY) + tstart;   // t=0 peeled, exact

        auto fstep = [&](float emv) {
            float s  = bcast_lane0(alpha);       // lane-0 alpha finite: valid shift
            float ue = __expf(alpha - s);        // -inf lanes -> 0
            xbuf[lane] = ue;                     // same-wave in-order LDS: no barrier
            const float4* uu = (const float4*)xbuf;
            v2f acc0 = {0.f, 0.f}, acc1 = {0.f, 0.f};
            #pragma unroll
            for (int g = 0; g < KS / 4; ++g) {
                float4 u = uu[g];
                v2f ua = {u.x, u.y}, ub = {u.z, u.w};
                v2f ea = {Erow[4 * g + 0], Erow[4 * g + 1]};
                v2f eb = {Erow[4 * g + 2], Erow[4 * g + 3]};
                acc0 = __builtin_elementwise_fma(ua, ea, acc0);
                acc1 = __builtin_elementwise_fma(ub, eb, acc1);
            }
            alpha = emv + s + __logf((acc0.x + acc0.y) + (acc1.x + acc1.y));
        };

        float em[PF];
        #pragma unroll
        for (int j = 0; j < PF; ++j)
            em[j] = act ? fb[(1 + j) * KS + lane] : -INFINITY;
        for (int c = 0; c < 63; ++c) {
            const int t0 = 1 + c * PF;
            float em_n[PF];
            #pragma unroll
            for (int j = 0; j < PF; ++j) {
                int tf = t0 + PF + j;
                em_n[j] = (act && tf < TLEN) ? fb[tf * KS + lane] : -INFINITY;
            }
            #pragma unroll
            for (int j = 0; j < PF; ++j) fstep(em[j]);
            #pragma unroll
            for (int j = 0; j < PF; ++j) em[j] = em_n[j];
        }
        #pragma unroll
        for (int j = 0; j < 7; ++j) fstep(em[j]);

        float tstop = act ? trans[STOP_S * KS + lane] : NEGV;
        if (lane == STOP_S) tstop = NEGV;
        float z = alpha + tstop;
        float mz = z;
        #pragma unroll
        for (int off = 32; off; off >>= 1)
            mz = fmaxf(mz, __shfl_xor(mz, off, 64));
        float se = __expf(z - mz);
        #pragma unroll
        for (int off = 32; off; off >>= 1)
            se += __shfl_xor(se, off, 64);
        float logZ = mz + __logf(se);

        float g = 0.0f;
        for (int t = lane; t < TLEN; t += 64) {
            int tg = tb[t];
            int pg = (t == 0) ? START_S : tb[t - 1];
            g += fb[t * KS + tg] + trans[tg * KS + pg];
        }
        #pragma unroll
        for (int off = 32; off; off >>= 1)
            g += __shfl_xor(g, off, 64);
        g += trans[STOP_S * KS + tb[TLEN - 1]];

        if (lane == 0) out[b] = logZ - g;
    } else {
        // ====== VITERBI: max-only scan (B-row store) + LDS-staged ballot chase =
        const int b = blockIdx.x - BN;
        const float* fb = feats + (size_t)b * TLEN * KS;
        float* vw = vw_g + (size_t)b * TLEN * KS;

        float Trow[KS];   // masked trans[next=lane][p] — reference's exact add
        {
            const float* tr = trans + (act ? lane : 0) * KS;
            #pragma unroll
            for (int p = 0; p < KS; ++p) {
                float tv = act ? tr[p] : NEGV;
                if (lane == START_S) tv = NEGV;
                if (p == STOP_S)     tv = NEGV;
                Trow[p] = tv;
            }
        }

        float vit = (lane == START_S) ? 0.0f : NEGV;
        float lastB = 0.0f;

        // R0's proven max-only core: zero compares, fp max exact.
        auto vstep = [&](float emv, int t) {
            xbuf[lane] = vit;                    // in-order LDS, no barrier
            const float4* ww = (const float4*)xbuf;
            v2f m0 = {-3.0e38f, -3.0e38f}, m1 = {-3.0e38f, -3.0e38f};
            #pragma unroll
            for (int g = 0; g < KS / 4; ++g) {
                float4 w = ww[g];
                v2f wa = {w.x, w.y}, wb = {w.z, w.w};
                v2f ta = {Trow[4 * g + 0], Trow[4 * g + 1]};
                v2f tc = {Trow[4 * g + 2], Trow[4 * g + 3]};
                m0 = __builtin_elementwise_max(m0, wa + ta);   // v_pk ops
                m1 = __builtin_elementwise_max(m1, wb + tc);
            }
            v2f mm = __builtin_elementwise_max(m0, m1);
            float B = fmaxf(mm.x, mm.y);         // pre-emission max row (exact)
            if (act) vw[t * KS + lane] = B;      // fire-and-forget, coalesced
            lastB = B;
            vit = B + emv;                       // reference's exact add
        };

        float em[PF];
        #pragma unroll
        for (int j = 0; j < PF; ++j)
            em[j] = act ? fb[j * KS + lane] : 0.0f;
        for (int c = 0; c < 64; ++c) {           // 512 = 64*8 exactly
            const int t0 = c * PF;
            float em_n[PF];
            if (c < 63) {
                #pragma unroll
                for (int j = 0; j < PF; ++j)
                    em_n[j] = act ? fb[(t0 + PF + j) * KS + lane] : 0.0f;
            }
            #pragma unroll
            for (int j = 0; j < PF; ++j) vstep(em[j], t0 + j);
            if (c < 63) {
                #pragma unroll
                for (int j = 0; j < PF; ++j) em[j] = em_n[j];
            }
        }

        // drain B stores before re-reading them in the chase
        asm volatile("s_waitcnt vmcnt(0)" ::: "memory");

        // ---- bt-phase LDS layout (aliases xbuf; same-wave in-order DS) ----
        float* trans_sh = (float*)pool;                    //  9216 B
        float* Bch      = (float*)(pool + 9216);           //  3072 B (16 rows)
        float* Ech      = (float*)(pool + 12288);          //  3072 B (16 rows)
        unsigned char* path_sh = pool + 15360;             //   512 B

        // stage masked trans (row-major [next][prev]) — R0 bits
        for (int idx = lane; idx < KS * KS; idx += 64) {
            int n = idx / KS, p = idx - n * KS;
            float tv = trans[idx];
            if (n == START_S) tv = NEGV;
            if (p == STOP_S)  tv = NEGV;
            trans_sh[idx] = tv;
        }

        float tstop = act ? trans[STOP_S * KS + lane] : NEGV;
        if (lane == STOP_S) tstop = NEGV;
        float term = act ? (vit + tstop) : -3.0e38f;
        float bv = term;
        int   bidx = act ? lane : 9999;
        wargmax(bv, bidx);                       // terminal only (once)
        int tag = __builtin_amdgcn_readfirstlane(bidx);
        if (lane == 0) {
            out[BN + b] = bv;
            path_sh[TLEN - 1] = (unsigned char)tag;
        }

        // ---- chunked ballot chase: 32 chunks x 16 rows of B and e ----
        // tag_{t-1} = first p with fl(B_{t-1}[p]+e_{t-1}[p]) + T[tag,p]
        //             == B_t[tag]   (R0-validated exact semantics)
        float Bcur = lastB;                      // B_t row, lane p holds [p]
        const int ll = act ? lane : 0;           // clamp inactive-lane addresses
        for (int c = 31; c >= 0; --c) {
            float4 tb_[3], te_[3];
            const float4* bs4 = (const float4*)(vw + (size_t)c * 16 * KS);
            const float4* es4 = (const float4*)(fb + (size_t)c * 16 * KS);
            #pragma unroll
            for (int i = 0; i < 3; ++i) {
                tb_[i] = bs4[lane + 64 * i];
                te_[i] = es4[lane + 64 * i];
            }
            // in-order DS: previous chunk's chase reads precede these writes
            #pragma unroll
            for (int i = 0; i < 3; ++i) {
                ((float4*)Bch)[lane + 64 * i] = tb_[i];
                ((float4*)Ech)[lane + 64 * i] = te_[i];
            }
            int thi = c * 16 + 16; if (thi > TLEN - 1) thi = TLEN - 1;
            const int tlo = c * 16 + 1;
            for (int t = thi; t >= tlo; --t) {
                float Bv = Bch[((t - 1) & 15) * KS + ll];   // B_{t-1}[lane]
                float Ev = Ech[((t - 1) & 15) * KS + ll];   // e_{t-1}[lane]
                float tr = trans_sh[tag * KS + ll];         // T[tag, lane]
                float v  = Bv + Ev;                         // scan's exact vit
                float sc = act ? (v + tr) : -INFINITY;      // scan's exact cand
                float bt = rlane(Bcur, tag);                // B_t[tag]
                unsigned long long mk =
                    __ballot(sc == bt) & ((1ULL << KS) - 1ULL);
                tag = __builtin_amdgcn_readfirstlane((int)__builtin_ctzll(mk));
                if (lane == 0) path_sh[t - 1] = (unsigned char)tag;
                Bcur = Bv;
            }
        }
        __syncthreads();   // single wave: drains LDS before the read-back
        float* pout = out + 2 * BN + (size_t)b * TLEN;
        for (int t = lane; t < TLEN; t += 64)
            pout[t] = (float)path_sh[t];
    }
}

extern "C" void kernel_launch(void* const* d_in, const int* in_sizes, int n_in,
                              void* d_out, int out_size, void* d_ws, size_t ws_size,
                              hipStream_t stream) {
    const float* feats = (const float*)d_in[0];
    const float* trans = (const float*)d_in[1];
    const int*   tags  = (const int*)d_in[2];
    float*       out   = (float*)d_out;
    (void)in_sizes; (void)n_in; (void)out_size; (void)ws_size;

    // workspace: [B, T, K] f32 B-rows = 100.7 MB (ws_size >= this, verified R0)
    crf16<<<dim3(2 * BN), dim3(64), 0, stream>>>(feats, trans, tags, out,
                                                 (float*)d_ws);
}